// Round 1
// baseline (2828.725 us; speedup 1.0000x reference)
//
#include <hip/hip_runtime.h>
#include <hip/hip_bf16.h>

// ---------------------------------------------------------------------------
// Wav2Vec-style feature extractor, fp32 baseline.
// conv0(1->512,k10,s5) -> time-norm+affine+gelu -> 4x conv(k3,s2)+gelu
// -> 2x conv(k2,s2)+gelu -> time-mean -> proj+relu -> per-sample MLP.
// ---------------------------------------------------------------------------

#define CC 512

__device__ __forceinline__ float gelu_tanh(float x) {
    // jax.nn.gelu(approximate=True): 0.5*x*(1+tanh(sqrt(2/pi)*(x+0.044715*x^3)))
    float x3 = x * x * x;
    float z  = 0.7978845608028654f * (x + 0.044715f * x3);
    float e  = __expf(2.0f * z);          // overflow -> inf -> th=1 ; underflow -> 0 -> th=-1
    float th = 1.0f - 2.0f / (e + 1.0f);
    return 0.5f * x * (1.0f + th);
}

// ---------------- conv0: cin=1, k=10, stride=5 -----------------------------
// grid (32 t-chunks, 64 co-groups, 8 b), block 256. out raw (pre-norm).
__global__ __launch_bounds__(256) void conv0_kernel(
    const float* __restrict__ x, const float* __restrict__ w0,
    float* __restrict__ out) {
    const int t0 = blockIdx.x * 256;
    const int cog = blockIdx.y, b = blockIdx.z;
    __shared__ float xs[256 * 5 + 10];
    for (int i = threadIdx.x; i < 256 * 5 + 5; i += 256) {
        int gi = t0 * 5 + i;
        xs[i] = (gi < 40000) ? x[b * 40000 + gi] : 0.0f;
    }
    __syncthreads();
    const int t = t0 + threadIdx.x;
    for (int cl = 0; cl < 8; ++cl) {
        const int co = cog * 8 + cl;
        const float* w = w0 + co * 10;
        float acc = 0.0f;
#pragma unroll
        for (int j = 0; j < 10; ++j) acc = fmaf(w[j], xs[threadIdx.x * 5 + j], acc);
        if (t < 7999) out[((size_t)b * CC + co) * 7999 + t] = acc;
    }
}

// ---------------- per-(b,c) stats over time (N=7999) -----------------------
__global__ __launch_bounds__(256) void gn_stats_kernel(
    const float* __restrict__ h, float* __restrict__ stats) {
    const int row = blockIdx.x;                 // b*512 + c
    const float* p = h + (size_t)row * 7999;
    float s = 0.0f, q = 0.0f;
    for (int i = threadIdx.x; i < 7999; i += 256) {
        float v = p[i];
        s += v; q += v * v;
    }
#pragma unroll
    for (int o = 32; o > 0; o >>= 1) {
        s += __shfl_down(s, o);
        q += __shfl_down(q, o);
    }
    __shared__ float ss[4], qq[4];
    const int wid = threadIdx.x >> 6, lane = threadIdx.x & 63;
    if (lane == 0) { ss[wid] = s; qq[wid] = q; }
    __syncthreads();
    if (threadIdx.x == 0) {
        float S = ss[0] + ss[1] + ss[2] + ss[3];
        float Q = qq[0] + qq[1] + qq[2] + qq[3];
        float mean = S / 7999.0f;
        float var  = fmaxf(Q / 7999.0f - mean * mean, 0.0f);
        stats[row * 2]     = mean;
        stats[row * 2 + 1] = rsqrtf(var + 1e-5f);
    }
}

// ---------------- normalize + affine + gelu (in place) ---------------------
// grid (32, 4096): y = row, x covers t.
__global__ __launch_bounds__(256) void gn_apply_gelu_kernel(
    float* __restrict__ h, const float* __restrict__ stats,
    const float* __restrict__ gsc, const float* __restrict__ gbi) {
    const int row = blockIdx.y;
    const int t = blockIdx.x * 256 + threadIdx.x;
    if (t >= 7999) return;
    const int c = row & (CC - 1);
    const float m = stats[row * 2], r = stats[row * 2 + 1];
    float v = h[(size_t)row * 7999 + t];
    v = (v - m) * r * gsc[c] + gbi[c];
    h[(size_t)row * 7999 + t] = gelu_tanh(v);
}

// ---------------- tiled stride-2 conv (512->512, k=K) + gelu ---------------
// grid (ceil(Lout/64), 8 co-tiles, 8 b), block 256.
// Per block: 64 co x 64 t output tile; K-loop over 16 ci-tiles of 32.
// Input staged parity-split (even/odd time phases) so stride-2 reads become
// contiguous float4 LDS reads. Weight tile [64][32*K] (+1 pad).
template <int K>
__global__ __launch_bounds__(256) void conv_gelu_kernel(
    const float* __restrict__ in, const float* __restrict__ w,
    float* __restrict__ out, int Lin, int Lout) {
    constexpr int TT = 64;              // t tile
    constexpr int CI = 32;              // ci tile
    constexpr int XW = (TT - 1) * 2 + K; // staged input width
    constexpr int XP = 68;              // X row pitch (16B aligned)
    constexpr int WP = CI * K + 1;      // W row pitch (pad: kills bank conflict)

    __shared__ __align__(16) float Xe[CI][XP];
    __shared__ __align__(16) float Xo[CI][XP];
    __shared__ float Ws[64][WP];

    const int t0 = blockIdx.x * TT;
    const int cob = blockIdx.y, b = blockIdx.z;
    const int tx = threadIdx.x & 15;    // 4 contiguous t per thread
    const int ty = threadIdx.x >> 4;    // 4 contiguous co per thread
    const int xg0 = t0 * 2;
    const size_t in_base = (size_t)b * CC * Lin;

    float acc[4][4] = {{0.f}};

    for (int cit = 0; cit < CC / CI; ++cit) {
        // stage X (parity split)
        for (int idx = threadIdx.x; idx < CI * XW; idx += 256) {
            const int ci = idx / XW, xx = idx - ci * XW;
            const int gx = xg0 + xx;
            float v = (gx < Lin) ? in[in_base + (size_t)(cit * CI + ci) * Lin + gx] : 0.0f;
            if (xx & 1) Xo[ci][xx >> 1] = v;
            else        Xe[ci][xx >> 1] = v;
        }
        // stage W
        const float* wsrc = w + (size_t)(cob * 64) * CC * K + cit * (CI * K);
        for (int idx = threadIdx.x; idx < 64 * CI * K; idx += 256) {
            const int co = idx / (CI * K), cj = idx - co * (CI * K);
            Ws[co][cj] = wsrc[(size_t)co * CC * K + cj];
        }
        __syncthreads();

#pragma unroll 2
        for (int ci = 0; ci < CI; ++ci) {
            const float4 xe = *(const float4*)&Xe[ci][tx * 4];
            const float4 xo = *(const float4*)&Xo[ci][tx * 4];
            float xv[K][4];
            xv[0][0] = xe.x; xv[0][1] = xe.y; xv[0][2] = xe.z; xv[0][3] = xe.w;
            xv[1][0] = xo.x; xv[1][1] = xo.y; xv[1][2] = xo.z; xv[1][3] = xo.w;
            if constexpr (K == 3) {
                const float xl = Xe[ci][tx * 4 + 4];
                xv[2][0] = xe.y; xv[2][1] = xe.z; xv[2][2] = xe.w; xv[2][3] = xl;
            }
#pragma unroll
            for (int i = 0; i < 4; ++i) {
                const float* wr = &Ws[ty * 4 + i][ci * K];
#pragma unroll
                for (int j = 0; j < K; ++j) {
                    const float wv = wr[j];
#pragma unroll
                    for (int u = 0; u < 4; ++u)
                        acc[i][u] = fmaf(wv, xv[j][u], acc[i][u]);
                }
            }
        }
        __syncthreads();
    }

    // epilogue: gelu + store
    const int t = t0 + tx * 4;
    const size_t ob = ((size_t)b * CC + cob * 64) * Lout;
#pragma unroll
    for (int i = 0; i < 4; ++i) {
        const size_t rb = ob + (size_t)(ty * 4 + i) * Lout;
#pragma unroll
        for (int u = 0; u < 4; ++u) {
            if (t + u < Lout) out[rb + t + u] = gelu_tanh(acc[i][u]);
        }
    }
}

// ---------------- time-mean + proj + relu ----------------------------------
// grid 8 (one per b), block 256.
__global__ __launch_bounds__(256) void feat_proj_kernel(
    const float* __restrict__ h,        // (8,512,124)
    const float* __restrict__ pw,       // (256,512)
    const float* __restrict__ pb,       // (256)
    float* __restrict__ pfeat) {        // (8,256)
    const int b = blockIdx.x;
    __shared__ float feat[CC];
    for (int c = threadIdx.x; c < CC; c += 256) {
        const float* p = h + ((size_t)b * CC + c) * 124;
        float s = 0.0f;
        for (int t = 0; t < 124; ++t) s += p[t];
        feat[c] = s * (1.0f / 124.0f);
    }
    __syncthreads();
    const int j = threadIdx.x;
    const float* wr = pw + (size_t)j * CC;
    float s = pb[j];
    for (int c = 0; c < CC; ++c) s = fmaf(feat[c], wr[c], s);
    pfeat[b * 256 + j] = fmaxf(s, 0.0f);
}

// ---------------- per-sample classifier MLP --------------------------------
// grid 8, block 128.
__global__ __launch_bounds__(128) void cls_kernel(
    const float* __restrict__ pfeat, const int* __restrict__ wid,
    const float* __restrict__ w1, const float* __restrict__ b1,
    const float* __restrict__ w2, const float* __restrict__ b2,
    float* __restrict__ out) {
    const int b = blockIdx.x;
    const int id = wid[b];
    __shared__ float pf[256], h1[128];
    for (int d = threadIdx.x; d < 256; d += 128) pf[d] = pfeat[b * 256 + d];
    __syncthreads();
    {
        const int hh = threadIdx.x;
        const float* w1p = w1 + (size_t)id * 256 * 128;
        float s = b1[id * 128 + hh];
        for (int d = 0; d < 256; ++d) s = fmaf(pf[d], w1p[d * 128 + hh], s);
        h1[hh] = fmaxf(s, 0.0f);
    }
    __syncthreads();
    if (threadIdx.x < 5) {
        const float* w2p = w2 + (size_t)id * 128 * 5;
        float s = b2[id * 5 + threadIdx.x];
        for (int hh = 0; hh < 128; ++hh) s = fmaf(h1[hh], w2p[hh * 5 + threadIdx.x], s);
        out[b * 5 + threadIdx.x] = s;
    }
}

// ---------------------------------------------------------------------------
extern "C" void kernel_launch(void* const* d_in, const int* in_sizes, int n_in,
                              void* d_out, int out_size, void* d_ws, size_t ws_size,
                              hipStream_t stream) {
    const float* x    = (const float*)d_in[0];
    const int*   wid  = (const int*)d_in[1];
    const float* gsc  = (const float*)d_in[2];
    const float* gbi  = (const float*)d_in[3];
    const float* pw   = (const float*)d_in[4];
    const float* pb   = (const float*)d_in[5];
    const float* w1   = (const float*)d_in[6];
    const float* b1   = (const float*)d_in[7];
    const float* w2   = (const float*)d_in[8];
    const float* b2   = (const float*)d_in[9];
    const float* cw[7];
    for (int i = 0; i < 7; ++i) cw[i] = (const float*)d_in[10 + i];

    // workspace layout
    const size_t BUFA_BYTES = (size_t)8 * CC * 7999 * 4;              // 131,055,616
    const size_t BUFB_OFF   = (BUFA_BYTES + 255) & ~(size_t)255;
    const size_t BUFB_BYTES = (size_t)8 * CC * 3999 * 4;              // 65,519,616
    const size_t STATS_OFF  = (BUFB_OFF + BUFB_BYTES + 255) & ~(size_t)255;
    char* ws = (char*)d_ws;
    float* bufA  = (float*)ws;
    float* bufB  = (float*)(ws + BUFB_OFF);
    float* stats = (float*)(ws + STATS_OFF);          // 4096 * {mean, rstd}
    float* pfeat = stats + 4096 * 2;                  // 8*256

    const int Ls[8] = {40000, 7999, 3999, 1999, 999, 499, 249, 124};

    // conv0 -> bufA (raw)
    conv0_kernel<<<dim3(32, 64, 8), 256, 0, stream>>>(x, cw[0], bufA);
    // per-row stats
    gn_stats_kernel<<<dim3(4096), 256, 0, stream>>>(bufA, stats);
    // normalize + affine + gelu (in place)
    gn_apply_gelu_kernel<<<dim3(32, 4096), 256, 0, stream>>>(bufA, stats, gsc, gbi);

    // conv1..conv6 ping-pong
    float* cur = bufA;
    float* nxt = bufB;
    for (int i = 1; i <= 6; ++i) {
        const int Lin = Ls[i], Lout = Ls[i + 1];
        dim3 grid((Lout + 63) / 64, 8, 8);
        if (i <= 4)
            conv_gelu_kernel<3><<<grid, 256, 0, stream>>>(cur, cw[i], nxt, Lin, Lout);
        else
            conv_gelu_kernel<2><<<grid, 256, 0, stream>>>(cur, cw[i], nxt, Lin, Lout);
        float* tmp = cur; cur = nxt; nxt = tmp;
    }

    // tail: mean + proj + relu, then per-sample MLP
    feat_proj_kernel<<<dim3(8), 256, 0, stream>>>(cur, pw, pb, pfeat);
    cls_kernel<<<dim3(8), 128, 0, stream>>>(pfeat, wid, w1, b1, w2, b2, (float*)d_out);
}

// Round 2
// 519.816 us; speedup vs baseline: 5.4418x; 5.4418x over previous
//
#include <hip/hip_runtime.h>
#include <hip/hip_bf16.h>

typedef unsigned short u16;
typedef short bf16x8 __attribute__((ext_vector_type(8)));
typedef float f32x4 __attribute__((ext_vector_type(4)));

#define CC 512

__device__ __forceinline__ float gelu_tanh(float x) {
    float x3 = x * x * x;
    float z  = 0.7978845608028654f * (x + 0.044715f * x3);
    float e  = __expf(2.0f * z);
    float th = 1.0f - 2.0f / (e + 1.0f);
    return 0.5f * x * (1.0f + th);
}

__device__ __forceinline__ u16 f2bf(float f) {
    union { float f; unsigned u; } v; v.f = f;
    unsigned r = v.u + 0x7fff + ((v.u >> 16) & 1);
    return (u16)(r >> 16);
}
__device__ __forceinline__ float bf2f(u16 h) {
    union { unsigned u; float f; } v; v.u = ((unsigned)h) << 16; return v.f;
}

// ---------------- conv0 + per-(b,c) partial stats (no materialization) -----
// grid (32 t-chunks of 250, 8 b), block 256.
__global__ __launch_bounds__(256) void conv0_stats(
    const float* __restrict__ x, const float* __restrict__ w0,
    float* __restrict__ part) {            // [b][512][32]{s,q}
    const int chunk = blockIdx.x, b = blockIdx.y;
    const int t0 = chunk * 250;
    __shared__ float xs[250 * 5 + 10];
    __shared__ float w0s[512 * 10];
    for (int i = threadIdx.x; i < 1260; i += 256) {
        int gi = t0 * 5 + i;
        xs[i] = (gi < 40000) ? x[b * 40000 + gi] : 0.0f;
    }
    for (int i = threadIdx.x; i < 5120; i += 256) w0s[i] = w0[i];
    __syncthreads();
    const int nt = min(250, 7999 - t0);
    for (int cc = 0; cc < 2; ++cc) {
        const int c = threadIdx.x * 2 + cc;
        const float* wr = &w0s[c * 10];
        float s = 0.0f, q = 0.0f;
        for (int t = 0; t < nt; ++t) {
            float a = 0.0f;
#pragma unroll
            for (int j = 0; j < 10; ++j) a = fmaf(wr[j], xs[t * 5 + j], a);
            s += a; q += a * a;
        }
        float* p = part + ((size_t)(b * 512 + c) * 32 + chunk) * 2;
        p[0] = s; p[1] = q;
    }
}

// grid (16), block 256: reduce 32 partials -> mean, rstd
__global__ __launch_bounds__(256) void stats_finalize(
    const float* __restrict__ part, float* __restrict__ stats) {
    const int row = blockIdx.x * 256 + threadIdx.x;   // 0..4095
    const float* p = part + (size_t)row * 32 * 2;
    float s = 0.0f, q = 0.0f;
    for (int k = 0; k < 32; ++k) { s += p[k * 2]; q += p[k * 2 + 1]; }
    float mean = s / 7999.0f;
    float var  = fmaxf(q / 7999.0f - mean * mean, 0.0f);
    stats[row * 2]     = mean;
    stats[row * 2 + 1] = rsqrtf(var + 1e-5f);
}

// ---------------- conv0 + norm + gelu -> transposed bf16 act [b][8320][512] -
// grid (260 t-chunks of 32, 8 b), block 256.
__global__ __launch_bounds__(256) void conv0_apply(
    const float* __restrict__ x, const float* __restrict__ w0,
    const float* __restrict__ stats, const float* __restrict__ gsc,
    const float* __restrict__ gbi, u16* __restrict__ actG) {
    const int t0 = blockIdx.x * 32, b = blockIdx.y;
    __shared__ float xs[32 * 5 + 10];
    __shared__ float w0s[512 * 10];
    __shared__ float A[512], Bb[512];
    for (int i = threadIdx.x; i < 170; i += 256) {
        int gi = t0 * 5 + i;
        xs[i] = (gi < 40000) ? x[b * 40000 + gi] : 0.0f;
    }
    for (int i = threadIdx.x; i < 5120; i += 256) w0s[i] = w0[i];
    for (int c = threadIdx.x; c < 512; c += 256) {
        float m = stats[(b * 512 + c) * 2], r = stats[(b * 512 + c) * 2 + 1];
        float a = r * gsc[c];
        A[c] = a; Bb[c] = gbi[c] - m * a;
    }
    __syncthreads();
    for (int tt = 0; tt < 32; ++tt) {
        const int t = t0 + tt;
        u16* orow = actG + ((size_t)b * 8320 + t) * 512;
#pragma unroll
        for (int half = 0; half < 2; ++half) {
            const int c = half * 256 + threadIdx.x;
            float g = 0.0f;
            if (t < 7999) {
                float a = 0.0f;
                const float* wr = &w0s[c * 10];
#pragma unroll
                for (int j = 0; j < 10; ++j) a = fmaf(wr[j], xs[tt * 5 + j], a);
                g = gelu_tanh(a * A[c] + Bb[c]);
            }
            orow[c] = f2bf(g);
        }
    }
}

// ---------------- weight pre-transform: [co][ci][j] fp32 -> padded hi/lo ---
// Wt layout: [cob(4)][cit(16)][co(128)][WROW=32K+8], pad zeroed.
template <int K>
__global__ __launch_bounds__(256) void wt_transform(
    const float* __restrict__ w, u16* __restrict__ whi, u16* __restrict__ wlo) {
    constexpr int WROW = 32 * K + 8;
    const int cit = blockIdx.x, cob = blockIdx.y;
    const size_t obase = ((size_t)(cob * 16 + cit)) * 128 * WROW;
    for (int idx = threadIdx.x; idx < 128 * WROW; idx += 256) {
        const int co = idx / WROW, e = idx % WROW;
        u16 hi = 0, lo = 0;
        if (e < 32 * K) {
            const int j = e >> 5, ci = e & 31;
            float v = w[((size_t)(cob * 128 + co) * 512 + cit * 32 + ci) * K + j];
            hi = f2bf(v);
            lo = f2bf(v - bf2f(hi));
        }
        whi[obase + idx] = hi;
        wlo[obase + idx] = lo;
    }
}

// ---------------- MFMA conv (512->512, k=K, stride 2) + gelu ---------------
// grid (ceil(Lout/128), 4 co-blocks, 8 b), block 256 (4 waves, 2co x 2t).
template <int K>
__global__ __launch_bounds__(256, 2) void conv_mfma(
    const u16* __restrict__ act, int capIn,
    const u16* __restrict__ wtHi, const u16* __restrict__ wtLo,
    u16* __restrict__ outAct, int capOut, int Lout) {
    constexpr int WROW = 32 * K + 8;
    constexpr int XH   = (K == 3) ? 136 : 128;   // xh pairs allocated
    constexpr int NXCH = XH * 8;                 // 16B chunks in X tile
    constexpr int NWCH = 128 * WROW / 8;         // 16B chunks per W plane

    __shared__ __align__(16) u16 Xs[XH * 64];
    __shared__ __align__(16) u16 Whi[128 * WROW];
    __shared__ __align__(16) u16 Wlo[128 * WROW];

    const int tid  = threadIdx.x;
    const int lane = tid & 63;
    const int wv   = tid >> 6;
    const int wco  = wv >> 1, wt = wv & 1;
    const int l15  = lane & 15, l16 = lane >> 4;
    const int t0   = blockIdx.x * 128;
    const int cob  = blockIdx.y;
    const int b    = blockIdx.z;
    const int x0   = t0 * 2;

    const char* abase  = (const char*)(act + (size_t)b * capIn * 512);
    const u16*  whBase = wtHi + (size_t)cob * 16 * 128 * WROW;
    const u16*  wlBase = wtLo + (size_t)cob * 16 * 128 * WROW;

    f32x4 acc[4][4] = {};

    for (int cit = 0; cit < 16; ++cit) {
        // ---- stage X tile (pre-swizzled global source, linear LDS dest) ----
        const char* asl = abase + cit * 64;   // ci0 * 2 bytes
        for (int cb = wv * 64; cb < NXCH; cb += 256) {
            const int c  = cb + lane;
            const int xh = c >> 3;
            const int ib = (c & 7) * 16;
            const int li = ib ^ ((xh & 7) << 4);
            int x = x0 + 2 * xh + (li >> 6);
            x = min(x, capIn - 1);
            const char* src = asl + (size_t)x * 1024 + (li & 63);
            __builtin_amdgcn_global_load_lds(
                (const __attribute__((address_space(1))) void*)src,
                (__attribute__((address_space(3))) void*)((char*)Xs + cb * 16),
                16, 0, 0);
        }
        // ---- stage W hi+lo (pure linear copy) ----
        const u16* ph = whBase + (size_t)cit * 128 * WROW;
        const u16* pl = wlBase + (size_t)cit * 128 * WROW;
        for (int cb = wv * 64; cb < NWCH; cb += 256) {
            const int c8 = (cb + lane) * 8;
            __builtin_amdgcn_global_load_lds(
                (const __attribute__((address_space(1))) void*)(ph + c8),
                (__attribute__((address_space(3))) void*)((char*)Whi + cb * 16),
                16, 0, 0);
            __builtin_amdgcn_global_load_lds(
                (const __attribute__((address_space(1))) void*)(pl + c8),
                (__attribute__((address_space(3))) void*)((char*)Wlo + cb * 16),
                16, 0, 0);
        }
        __syncthreads();

#pragma unroll
        for (int j = 0; j < K; ++j) {
            bf16x8 bt[4], ah[4], al[4];
#pragma unroll
            for (int tf = 0; tf < 4; ++tf) {
                const int tl = wt * 64 + tf * 16 + l15;
                const int xl = 2 * tl + j;
                const int xh = xl >> 1, p = xl & 1;
                const int off = xh * 128 + ((p * 64 + l16 * 16) ^ ((xh & 7) << 4));
                bt[tf] = *(const bf16x8*)((const char*)Xs + off);
            }
#pragma unroll
            for (int cf = 0; cf < 4; ++cf) {
                const int ro = (wco * 64 + cf * 16 + l15) * WROW + j * 32 + l16 * 8;
                ah[cf] = *(const bf16x8*)(Whi + ro);
                al[cf] = *(const bf16x8*)(Wlo + ro);
            }
#pragma unroll
            for (int cf = 0; cf < 4; ++cf)
#pragma unroll
                for (int tf = 0; tf < 4; ++tf) {
                    acc[cf][tf] = __builtin_amdgcn_mfma_f32_16x16x32_bf16(
                        ah[cf], bt[tf], acc[cf][tf], 0, 0, 0);
                    acc[cf][tf] = __builtin_amdgcn_mfma_f32_16x16x32_bf16(
                        al[cf], bt[tf], acc[cf][tf], 0, 0, 0);
                }
        }
        __syncthreads();
    }

    // ---- epilogue: gelu + bf16, transposed store [b][t][512] ----
    u16* ob = outAct + (size_t)b * capOut * 512;
#pragma unroll
    for (int cf = 0; cf < 4; ++cf) {
#pragma unroll
        for (int tf = 0; tf < 4; ++tf) {
            const int tG  = t0 + wt * 64 + tf * 16 + l15;
            const int coG = cob * 128 + wco * 64 + cf * 16 + l16 * 4;
            union { u16 s[4]; uint2 v; } pk;
#pragma unroll
            for (int r = 0; r < 4; ++r) {
                float v = acc[cf][tf][r];
                float g = (tG < Lout) ? gelu_tanh(v) : 0.0f;
                pk.s[r] = f2bf(g);
            }
            *(uint2*)(ob + (size_t)tG * 512 + coG) = pk.v;
        }
    }
}

// ---------------- zero pad rows [r0,r1) of act buffer ----------------------
__global__ __launch_bounds__(256) void padzero(u16* buf, int cap, int r0, int r1) {
    const int n = (r1 - r0) * 512;
    for (int i = blockIdx.x * 256 + threadIdx.x; i < 8 * n; i += gridDim.x * 256) {
        const int b = i / n, rem = i - b * n;
        buf[((size_t)b * cap + r0) * 512 + rem] = 0;
    }
}

// ---------------- time-mean + proj + relu ----------------------------------
__global__ __launch_bounds__(256) void feat_proj_kernel(
    const u16* __restrict__ act, int cap,
    const float* __restrict__ pw, const float* __restrict__ pb,
    float* __restrict__ pfeat) {
    const int b = blockIdx.x;
    __shared__ float feat[CC];
    for (int half = 0; half < 2; ++half) {
        const int c = half * 256 + threadIdx.x;
        float s = 0.0f;
        for (int t = 0; t < 124; ++t) s += bf2f(act[((size_t)b * cap + t) * 512 + c]);
        feat[c] = s * (1.0f / 124.0f);
    }
    __syncthreads();
    const int j = threadIdx.x;
    const float* wr = pw + (size_t)j * CC;
    float s = pb[j];
    for (int c = 0; c < CC; ++c) s = fmaf(feat[c], wr[c], s);
    pfeat[b * 256 + j] = fmaxf(s, 0.0f);
}

// ---------------- per-sample classifier MLP --------------------------------
__global__ __launch_bounds__(128) void cls_kernel(
    const float* __restrict__ pfeat, const int* __restrict__ wid,
    const float* __restrict__ w1, const float* __restrict__ b1,
    const float* __restrict__ w2, const float* __restrict__ b2,
    float* __restrict__ out) {
    const int b = blockIdx.x;
    const int id = wid[b];
    __shared__ float pf[256], h1[128];
    for (int d = threadIdx.x; d < 256; d += 128) pf[d] = pfeat[b * 256 + d];
    __syncthreads();
    {
        const int hh = threadIdx.x;
        const float* w1p = w1 + (size_t)id * 256 * 128;
        float s = b1[id * 128 + hh];
        for (int d = 0; d < 256; ++d) s = fmaf(pf[d], w1p[d * 128 + hh], s);
        h1[hh] = fmaxf(s, 0.0f);
    }
    __syncthreads();
    if (threadIdx.x < 5) {
        const float* w2p = w2 + (size_t)id * 128 * 5;
        float s = b2[id * 5 + threadIdx.x];
        for (int hh = 0; hh < 128; ++hh) s = fmaf(h1[hh], w2p[hh * 5 + threadIdx.x], s);
        out[b * 5 + threadIdx.x] = s;
    }
}

// ---------------------------------------------------------------------------
extern "C" void kernel_launch(void* const* d_in, const int* in_sizes, int n_in,
                              void* d_out, int out_size, void* d_ws, size_t ws_size,
                              hipStream_t stream) {
    const float* x   = (const float*)d_in[0];
    const int*   wid = (const int*)d_in[1];
    const float* gsc = (const float*)d_in[2];
    const float* gbi = (const float*)d_in[3];
    const float* pw  = (const float*)d_in[4];
    const float* pb  = (const float*)d_in[5];
    const float* w1  = (const float*)d_in[6];
    const float* b1  = (const float*)d_in[7];
    const float* w2  = (const float*)d_in[8];
    const float* b2  = (const float*)d_in[9];
    const float* cw[7];
    for (int i = 0; i < 7; ++i) cw[i] = (const float*)d_in[10 + i];

    // ---- workspace layout (bytes) ----
    char* ws = (char*)d_ws;
    const size_t SZ_ACTG = (size_t)8 * 8320 * 512 * 2;   // 68,157,440
    const size_t SZ_P    = (size_t)8 * 4224 * 512 * 2;   // 34,603,008
    const size_t SZ_Q    = (size_t)8 * 2176 * 512 * 2;   // 17,825,792
    u16* actG = (u16*)ws;
    u16* bufP = (u16*)(ws + SZ_ACTG);
    u16* bufQ = (u16*)(ws + SZ_ACTG + SZ_P);
    size_t off = SZ_ACTG + SZ_P + SZ_Q;
    // weight transforms: layers 1..4 K=3 (plane 851,968 elems), 5..6 K=2 (589,824)
    u16* wtHi[7]; u16* wtLo[7];
    for (int i = 1; i <= 6; ++i) {
        const size_t plane = (i <= 4) ? (size_t)64 * 128 * 104 : (size_t)64 * 128 * 72;
        wtHi[i] = (u16*)(ws + off); off += plane * 2;
        wtLo[i] = (u16*)(ws + off); off += plane * 2;
    }
    off = (off + 255) & ~(size_t)255;
    float* statsPart = (float*)(ws + off); off += (size_t)8 * 512 * 32 * 2 * 4;
    float* stats     = (float*)(ws + off); off += 4096 * 2 * 4;
    float* pfeat     = (float*)(ws + off); off += 8 * 256 * 4;

    // ---- conv0 + stats + apply (-> actG bf16, transposed, zero-padded) ----
    conv0_stats<<<dim3(32, 8), 256, 0, stream>>>(x, cw[0], statsPart);
    stats_finalize<<<dim3(16), 256, 0, stream>>>(statsPart, stats);
    conv0_apply<<<dim3(260, 8), 256, 0, stream>>>(x, cw[0], stats, gsc, gbi, actG);

    // ---- weight pre-transforms ----
    for (int i = 1; i <= 4; ++i)
        wt_transform<3><<<dim3(16, 4), 256, 0, stream>>>(cw[i], wtHi[i], wtLo[i]);
    for (int i = 5; i <= 6; ++i)
        wt_transform<2><<<dim3(16, 4), 256, 0, stream>>>(cw[i], wtHi[i], wtLo[i]);

    // ---- conv chain ----
    // 1: actG(8320) -> P(4224), Lout 3999, pad [4096,4112)
    conv_mfma<3><<<dim3(32, 4, 8), 256, 0, stream>>>(actG, 8320, wtHi[1], wtLo[1], bufP, 4224, 3999);
    padzero<<<dim3(32), 256, 0, stream>>>(bufP, 4224, 4096, 4112);
    // 2: P -> Q, Lout 1999, pad [2048,2064)
    conv_mfma<3><<<dim3(16, 4, 8), 256, 0, stream>>>(bufP, 4224, wtHi[2], wtLo[2], bufQ, 2176, 1999);
    padzero<<<dim3(32), 256, 0, stream>>>(bufQ, 2176, 2048, 2064);
    // 3: Q -> P, Lout 999, pad [1024,1040)
    conv_mfma<3><<<dim3(8, 4, 8), 256, 0, stream>>>(bufQ, 2176, wtHi[3], wtLo[3], bufP, 4224, 999);
    padzero<<<dim3(32), 256, 0, stream>>>(bufP, 4224, 1024, 1040);
    // 4: P -> Q, Lout 499
    conv_mfma<3><<<dim3(4, 4, 8), 256, 0, stream>>>(bufP, 4224, wtHi[4], wtLo[4], bufQ, 2176, 499);
    // 5: Q -> P, Lout 249 (K=2)
    conv_mfma<2><<<dim3(2, 4, 8), 256, 0, stream>>>(bufQ, 2176, wtHi[5], wtLo[5], bufP, 4224, 249);
    // 6: P -> Q, Lout 124 (K=2)
    conv_mfma<2><<<dim3(1, 4, 8), 256, 0, stream>>>(bufP, 4224, wtHi[6], wtLo[6], bufQ, 2176, 124);

    // ---- tail ----
    feat_proj_kernel<<<dim3(8), 256, 0, stream>>>(bufQ, 2176, pw, pb, pfeat);
    cls_kernel<<<dim3(8), 128, 0, stream>>>(pfeat, wid, w1, b1, w2, b2, (float*)d_out);
}

// Round 3
// 391.729 us; speedup vs baseline: 7.2211x; 1.3270x over previous
//
#include <hip/hip_runtime.h>
#include <hip/hip_bf16.h>

typedef unsigned short u16;
typedef short bf16x8 __attribute__((ext_vector_type(8)));
typedef float f32x4 __attribute__((ext_vector_type(4)));

#define CC 512

__device__ __forceinline__ float gelu_tanh(float x) {
    float x3 = x * x * x;
    float z  = 0.7978845608028654f * (x + 0.044715f * x3);
    float e  = __expf(2.0f * z);
    float th = 1.0f - 2.0f / (e + 1.0f);
    return 0.5f * x * (1.0f + th);
}

__device__ __forceinline__ u16 f2bf(float f) {
    union { float f; unsigned u; } v; v.f = f;
    unsigned r = v.u + 0x7fff + ((v.u >> 16) & 1);
    return (u16)(r >> 16);
}
__device__ __forceinline__ float bf2f(u16 h) {
    union { unsigned u; float f; } v; v.u = ((unsigned)h) << 16; return v.f;
}

// ---------------- conv0 + per-(b,c) partial stats --------------------------
__global__ __launch_bounds__(256) void conv0_stats(
    const float* __restrict__ x, const float* __restrict__ w0,
    float* __restrict__ part) {            // [b*512+c][32]{s,q}
    const int chunk = blockIdx.x, b = blockIdx.y;
    const int t0 = chunk * 250;
    __shared__ float xs[250 * 5 + 10];
    __shared__ float w0s[512 * 10];
    for (int i = threadIdx.x; i < 1260; i += 256) {
        int gi = t0 * 5 + i;
        xs[i] = (gi < 40000) ? x[b * 40000 + gi] : 0.0f;
    }
    for (int i = threadIdx.x; i < 5120; i += 256) w0s[i] = w0[i];
    __syncthreads();
    const int nt = min(250, 7999 - t0);
    for (int cc = 0; cc < 2; ++cc) {
        const int c = threadIdx.x * 2 + cc;
        const float* wr = &w0s[c * 10];
        float s = 0.0f, q = 0.0f;
        for (int t = 0; t < nt; ++t) {
            float a = 0.0f;
#pragma unroll
            for (int j = 0; j < 10; ++j) a = fmaf(wr[j], xs[t * 5 + j], a);
            s += a; q += a * a;
        }
        float* p = part + ((size_t)(b * 512 + c) * 32 + chunk) * 2;
        p[0] = s; p[1] = q;
    }
}

__global__ __launch_bounds__(256) void stats_finalize(
    const float* __restrict__ part, float* __restrict__ stats) {
    const int row = blockIdx.x * 256 + threadIdx.x;   // 0..4095
    const float* p = part + (size_t)row * 32 * 2;
    float s = 0.0f, q = 0.0f;
    for (int k = 0; k < 32; ++k) { s += p[k * 2]; q += p[k * 2 + 1]; }
    float mean = s / 7999.0f;
    float var  = fmaxf(q / 7999.0f - mean * mean, 0.0f);
    stats[row * 2]     = mean;
    stats[row * 2 + 1] = rsqrtf(var + 1e-5f);
}

// ---------------- conv0 + norm + gelu -> bf16 act [b][8320][512] -----------
// grid (260, 8), block 256. Vectorized uint4 stores; zero rows t>=7999.
__global__ __launch_bounds__(256) void conv0_apply(
    const float* __restrict__ x, const float* __restrict__ w0,
    const float* __restrict__ stats, const float* __restrict__ gsc,
    const float* __restrict__ gbi, u16* __restrict__ actG) {
    const int t0 = blockIdx.x * 32, b = blockIdx.y;
    __shared__ float xs[32 * 5 + 16];
    __shared__ float w0s[512 * 10];
    __shared__ float A[512], Bb[512];
    for (int i = threadIdx.x; i < 170; i += 256) {
        int gi = t0 * 5 + i;
        xs[i] = (gi < 40000) ? x[b * 40000 + gi] : 0.0f;
    }
    for (int i = threadIdx.x; i < 5120; i += 256) w0s[i] = w0[i];
    for (int c = threadIdx.x; c < 512; c += 256) {
        float m = stats[(b * 512 + c) * 2], r = stats[(b * 512 + c) * 2 + 1];
        float a = r * gsc[c];
        A[c] = a; Bb[c] = gbi[c] - m * a;
    }
    __syncthreads();
    const int c0 = (threadIdx.x & 63) * 8;
    const int wv = threadIdx.x >> 6;          // tt block of 8
    u16 res[8][8];                            // [tt][q], static-indexed
#pragma unroll
    for (int q = 0; q < 8; ++q) {
        const int c = c0 + q;
        float wreg[10];
#pragma unroll
        for (int j = 0; j < 10; ++j) wreg[j] = w0s[c * 10 + j];
        const float Ar = A[c], Br = Bb[c];
#pragma unroll
        for (int u = 0; u < 8; ++u) {
            const int tt = wv * 8 + u;
            float a = 0.0f;
#pragma unroll
            for (int j = 0; j < 10; ++j) a = fmaf(wreg[j], xs[tt * 5 + j], a);
            res[u][q] = f2bf(gelu_tanh(fmaf(a, Ar, Br)));
        }
    }
#pragma unroll
    for (int u = 0; u < 8; ++u) {
        const int t = t0 + wv * 8 + u;
        union { u16 s[8]; uint4 v; } pk;
#pragma unroll
        for (int q = 0; q < 8; ++q) pk.s[q] = (t < 7999) ? res[u][q] : (u16)0;
        *(uint4*)(actG + ((size_t)b * 8320 + t) * 512 + c0) = pk.v;
    }
}

// ---------------- weight pre-transform (hi only), batched ------------------
template <int K, int NL>
struct WtBatch { const float* src[NL]; u16* dst[NL]; };

template <int K, int NL>
__global__ __launch_bounds__(256) void wt_transform(WtBatch<K, NL> a) {
    constexpr int WROW = 32 * K + 8;
    const int cit = blockIdx.x, cob = blockIdx.y, l = blockIdx.z;
    const float* w = a.src[l];
    u16* dst = a.dst[l] + ((size_t)(cob * 16 + cit)) * 128 * WROW;
    for (int idx = threadIdx.x; idx < 128 * WROW; idx += 256) {
        const int co = idx / WROW, e = idx - co * WROW;
        u16 hi = 0;
        if (e < 32 * K) {
            const int j = e >> 5, ci = e & 31;
            hi = f2bf(w[((size_t)(cob * 128 + co) * 512 + cit * 32 + ci) * K + j]);
        }
        dst[idx] = hi;
    }
}

// ---------------- MFMA conv (512->512, k=K, stride 2) + gelu ---------------
// Block tile 128co x TTt, 4 waves (2co x 2t), reg-tile 4 x TT/32.
// Double-buffered X+W with 2-phase counted pipeline.
template <int K, int TT>
__global__ __launch_bounds__(256, 1) void conv_mfma(
    const u16* __restrict__ act, int capIn,
    const u16* __restrict__ wt,
    u16* __restrict__ outAct, int capOut, int Lout) {
    constexpr int WROW = 32 * K + 8;
    constexpr int XH   = TT + 4;
    constexpr int TF   = TT / 32;
    constexpr int NXCH = XH * 8;
    constexpr int NWCH = 128 * WROW * 2 / 16;

    __shared__ __align__(16) u16 Xs[2][XH * 64];
    __shared__ __align__(16) u16 Ws[2][128 * WROW];

    const int tid  = threadIdx.x;
    const int lane = tid & 63;
    const int wv   = tid >> 6;
    const int wco  = wv >> 1, wtt = wv & 1;
    const int l15  = lane & 15, l16 = lane >> 4;
    const int t0   = blockIdx.x * TT;
    const int cob  = blockIdx.y;
    const int b    = blockIdx.z;
    const int x0   = t0 * 2;

    const char* abase = (const char*)(act + (size_t)b * capIn * 512);
    const u16*  wbase = wt + (size_t)cob * 16 * 128 * WROW;

    auto stageX = [&](int buf, int cit) {
        const char* asl = abase + cit * 64;
#pragma unroll
        for (int k = 0; k < (NXCH + 255) / 256; ++k) {
            const int cb = wv * 64 + k * 256;
            const int c  = cb + lane;
            if (cb < NXCH && c < NXCH) {
                const int xh = c >> 3;
                const int li = ((c & 7) * 16) ^ ((xh & 7) << 4);
                int x = x0 + 2 * xh + (li >> 6);
                x = min(x, capIn - 1);
                __builtin_amdgcn_global_load_lds(
                    (const __attribute__((address_space(1))) void*)(asl + (size_t)x * 1024 + (li & 63)),
                    (__attribute__((address_space(3))) void*)((char*)&Xs[buf][0] + cb * 16),
                    16, 0, 0);
            }
        }
    };
    auto stageW = [&](int buf, int cit) {
        const char* psrc = (const char*)(wbase + (size_t)cit * 128 * WROW);
#pragma unroll
        for (int k = 0; k < (NWCH + 255) / 256; ++k) {
            const int cb = wv * 64 + k * 256;
            if (cb < NWCH && cb + lane < NWCH) {
                __builtin_amdgcn_global_load_lds(
                    (const __attribute__((address_space(1))) void*)(psrc + (size_t)(cb + lane) * 16),
                    (__attribute__((address_space(3))) void*)((char*)&Ws[buf][0] + cb * 16),
                    16, 0, 0);
            }
        }
    };

    // cit-invariant ds_read byte offsets (all statically indexed -> registers)
    int xoff[K][TF];
    int woff[K][4];
#pragma unroll
    for (int j = 0; j < K; ++j) {
#pragma unroll
        for (int tf = 0; tf < TF; ++tf) {
            const int tl = wtt * (TT / 2) + tf * 16 + l15;
            const int xl = 2 * tl + j;
            const int xh = xl >> 1, p = xl & 1;
            xoff[j][tf] = xh * 128 + ((p * 64 + l16 * 16) ^ ((xh & 7) << 4));
        }
#pragma unroll
        for (int cf = 0; cf < 4; ++cf)
            woff[j][cf] = ((wco * 64 + cf * 16 + l15) * WROW + j * 32 + l16 * 8) * 2;
    }

    f32x4 acc[4][TF] = {};

    stageX(0, 0); stageW(0, 0);
    asm volatile("s_waitcnt vmcnt(0)");
    __syncthreads();

    for (int cit = 0; cit < 16; ++cit) {
        const int cur = cit & 1;
        if (cit < 15) { stageX(cur ^ 1, cit + 1); stageW(cur ^ 1, cit + 1); }
        const char* xb = (const char*)&Xs[cur][0];
        const char* wb = (const char*)&Ws[cur][0];
#pragma unroll
        for (int j = 0; j < K; ++j) {
            bf16x8 bt[TF], ah[4];
#pragma unroll
            for (int tf = 0; tf < TF; ++tf) bt[tf] = *(const bf16x8*)(xb + xoff[j][tf]);
#pragma unroll
            for (int cf = 0; cf < 4; ++cf) ah[cf] = *(const bf16x8*)(wb + woff[j][cf]);
#pragma unroll
            for (int cf = 0; cf < 4; ++cf)
#pragma unroll
                for (int tf = 0; tf < TF; ++tf)
                    acc[cf][tf] = __builtin_amdgcn_mfma_f32_16x16x32_bf16(
                        ah[cf], bt[tf], acc[cf][tf], 0, 0, 0);
        }
        asm volatile("s_waitcnt vmcnt(0)");
        __syncthreads();
    }

    // epilogue: gelu + bf16 transposed store [b][t][512]
    u16* ob = outAct + (size_t)b * capOut * 512;
#pragma unroll
    for (int cf = 0; cf < 4; ++cf) {
#pragma unroll
        for (int tf = 0; tf < TF; ++tf) {
            const int tG  = t0 + wtt * (TT / 2) + tf * 16 + l15;
            const int coG = cob * 128 + wco * 64 + cf * 16 + l16 * 4;
            union { u16 s[4]; uint2 v; } pk;
#pragma unroll
            for (int r = 0; r < 4; ++r)
                pk.s[r] = f2bf(gelu_tanh(acc[cf][tf][r]));
            *(uint2*)(ob + (size_t)tG * 512 + coG) = pk.v;
        }
    }
}

// ---------------- time-mean + proj + relu ----------------------------------
__global__ __launch_bounds__(512) void feat_proj_kernel(
    const u16* __restrict__ act, int cap,
    const float* __restrict__ pw, const float* __restrict__ pb,
    float* __restrict__ pfeat) {
    const int b = blockIdx.x;
    __shared__ float feat[CC];
    const int c = threadIdx.x;
    float s = 0.0f;
    for (int t = 0; t < 124; ++t) s += bf2f(act[((size_t)b * cap + t) * 512 + c]);
    feat[c] = s * (1.0f / 124.0f);
    __syncthreads();
    if (threadIdx.x < 256) {
        const int j = threadIdx.x;
        const float* wr = pw + (size_t)j * CC;
        float acc = pb[j];
        for (int cc = 0; cc < CC; ++cc) acc = fmaf(feat[cc], wr[cc], acc);
        pfeat[b * 256 + j] = fmaxf(acc, 0.0f);
    }
}

// ---------------- per-sample classifier MLP --------------------------------
__global__ __launch_bounds__(128) void cls_kernel(
    const float* __restrict__ pfeat, const int* __restrict__ wid,
    const float* __restrict__ w1, const float* __restrict__ b1,
    const float* __restrict__ w2, const float* __restrict__ b2,
    float* __restrict__ out) {
    const int b = blockIdx.x;
    const int id = wid[b];
    __shared__ float pf[256], h1[128];
    for (int d = threadIdx.x; d < 256; d += 128) pf[d] = pfeat[b * 256 + d];
    __syncthreads();
    {
        const int hh = threadIdx.x;
        const float* w1p = w1 + (size_t)id * 256 * 128;
        float s = b1[id * 128 + hh];
        for (int d = 0; d < 256; ++d) s = fmaf(pf[d], w1p[d * 128 + hh], s);
        h1[hh] = fmaxf(s, 0.0f);
    }
    __syncthreads();
    if (threadIdx.x < 5) {
        const float* w2p = w2 + (size_t)id * 128 * 5;
        float s = b2[id * 5 + threadIdx.x];
        for (int hh = 0; hh < 128; ++hh) s = fmaf(h1[hh], w2p[hh * 5 + threadIdx.x], s);
        out[b * 5 + threadIdx.x] = s;
    }
}

// ---------------------------------------------------------------------------
extern "C" void kernel_launch(void* const* d_in, const int* in_sizes, int n_in,
                              void* d_out, int out_size, void* d_ws, size_t ws_size,
                              hipStream_t stream) {
    const float* x   = (const float*)d_in[0];
    const int*   wid = (const int*)d_in[1];
    const float* gsc = (const float*)d_in[2];
    const float* gbi = (const float*)d_in[3];
    const float* pw  = (const float*)d_in[4];
    const float* pb  = (const float*)d_in[5];
    const float* w1  = (const float*)d_in[6];
    const float* b1  = (const float*)d_in[7];
    const float* w2  = (const float*)d_in[8];
    const float* b2  = (const float*)d_in[9];
    const float* cw[7];
    for (int i = 0; i < 7; ++i) cw[i] = (const float*)d_in[10 + i];

    // ---- workspace layout ----
    char* ws = (char*)d_ws;
    const size_t SZ_ACTG = (size_t)8 * 8320 * 512 * 2;
    const size_t SZ_P    = (size_t)8 * 4224 * 512 * 2;
    const size_t SZ_Q    = (size_t)8 * 2176 * 512 * 2;
    u16* actG = (u16*)ws;
    u16* bufP = (u16*)(ws + SZ_ACTG);
    u16* bufQ = (u16*)(ws + SZ_ACTG + SZ_P);
    size_t off = SZ_ACTG + SZ_P + SZ_Q;
    u16* wtbuf[7];
    for (int i = 1; i <= 4; ++i) { wtbuf[i] = (u16*)(ws + off); off += (size_t)64 * 128 * 104 * 2; }
    for (int i = 5; i <= 6; ++i) { wtbuf[i] = (u16*)(ws + off); off += (size_t)64 * 128 * 72 * 2; }
    off = (off + 255) & ~(size_t)255;
    float* statsPart = (float*)(ws + off); off += (size_t)4096 * 32 * 2 * 4;
    float* stats     = (float*)(ws + off); off += 4096 * 2 * 4;
    float* pfeat     = (float*)(ws + off); off += 8 * 256 * 4;

    // ---- conv0 + stats + apply ----
    conv0_stats<<<dim3(32, 8), 256, 0, stream>>>(x, cw[0], statsPart);
    stats_finalize<<<dim3(16), 256, 0, stream>>>(statsPart, stats);
    conv0_apply<<<dim3(260, 8), 256, 0, stream>>>(x, cw[0], stats, gsc, gbi, actG);

    // ---- weight pre-transforms (2 launches) ----
    {
        WtBatch<3, 4> a;
        for (int i = 0; i < 4; ++i) { a.src[i] = cw[1 + i]; a.dst[i] = wtbuf[1 + i]; }
        wt_transform<3, 4><<<dim3(16, 4, 4), 256, 0, stream>>>(a);
        WtBatch<2, 2> c;
        for (int i = 0; i < 2; ++i) { c.src[i] = cw[5 + i]; c.dst[i] = wtbuf[5 + i]; }
        wt_transform<2, 2><<<dim3(16, 4, 2), 256, 0, stream>>>(c);
    }

    // ---- conv chain (no padzero: out-of-range rows are benign garbage) ----
    conv_mfma<3, 256><<<dim3(16, 4, 8), 256, 0, stream>>>(actG, 8320, wtbuf[1], bufP, 4224, 3999);
    conv_mfma<3, 256><<<dim3( 8, 4, 8), 256, 0, stream>>>(bufP, 4224, wtbuf[2], bufQ, 2176, 1999);
    conv_mfma<3, 128><<<dim3( 8, 4, 8), 256, 0, stream>>>(bufQ, 2176, wtbuf[3], bufP, 4224,  999);
    conv_mfma<3, 128><<<dim3( 4, 4, 8), 256, 0, stream>>>(bufP, 4224, wtbuf[4], bufQ, 2176,  499);
    conv_mfma<2, 128><<<dim3( 2, 4, 8), 256, 0, stream>>>(bufQ, 2176, wtbuf[5], bufP, 4224,  249);
    conv_mfma<2, 128><<<dim3( 1, 4, 8), 256, 0, stream>>>(bufP, 4224, wtbuf[6], bufQ, 2176,  124);

    // ---- tail ----
    feat_proj_kernel<<<dim3(8), 512, 0, stream>>>(bufQ, 2176, pw, pb, pfeat);
    cls_kernel<<<dim3(8), 128, 0, stream>>>(pfeat, wid, w1, b1, w2, b2, (float*)d_out);
}